// Round 1
// baseline (107.559 us; speedup 1.0000x reference)
//
#include <hip/hip_runtime.h>
#include <math.h>

// Trig table layout in d_ws / LDS (float2 = {cos, sin}):
//   [0,16)    conv1_w: [oc*4 + e], e = a*2+c  (matches conv1_w flat layout)
//   [16,528)  conv2_w: [e*8 + oc], e = ch*16+ki*4+kj  (transposed for bank-friendly reads)
//   [528,3408) ff_w:   [k*10 + n] (matches ff_w flat layout)
#define NTRIG 3408
#define W1_OFF 0
#define W2_OFF 16
#define FF_OFF 528

__global__ void precompute_trig(const float* __restrict__ w1,
                                const float* __restrict__ w2,
                                const float* __restrict__ ff,
                                float2* __restrict__ out) {
    int idx = blockIdx.x * blockDim.x + threadIdx.x;
    if (idx < 16) {
        float s, c; sincosf(w1[idx], &s, &c);
        out[W1_OFF + idx] = make_float2(c, s);
    }
    if (idx < 512) {
        int oc = idx >> 6, e = idx & 63;
        float s, c; sincosf(w2[idx], &s, &c);
        out[W2_OFF + e * 8 + oc] = make_float2(c, s);
    }
    if (idx < 2880) {
        float s, c; sincosf(ff[idx], &s, &c);
        out[FF_OFF + idx] = make_float2(c, s);
    }
}

template <bool USE_WS>
__global__ __launch_bounds__(320) void ringnn_kernel(
    const float* __restrict__ x,
    const float* __restrict__ w1g,
    const float* __restrict__ w2g,
    const float* __restrict__ ffg,
    const float2* __restrict__ trig_ws,
    float* __restrict__ out)
{
    __shared__ float2 trig[NTRIG];
    __shared__ float2 sc1[784];   // [ch*196 + pos], pos = i*14+j ; {sin,cos} of h1
    __shared__ float2 sc2[288];   // [pos*8 + oc], pos = oi*6+oj  ; {sin,cos} of h2

    const int tid = threadIdx.x;
    const int b = blockIdx.x;

    // ---- load (or compute) weight trig tables into LDS ----
    if (USE_WS) {
        for (int i = tid; i < NTRIG; i += 320) trig[i] = trig_ws[i];
    } else {
        for (int i = tid; i < 16; i += 320) {
            float s, c; sincosf(w1g[i], &s, &c);
            trig[W1_OFF + i] = make_float2(c, s);
        }
        for (int i = tid; i < 512; i += 320) {
            int oc = i >> 6, e = i & 63;
            float s, c; sincosf(w2g[i], &s, &c);
            trig[W2_OFF + e * 8 + oc] = make_float2(c, s);
        }
        for (int i = tid; i < 2880; i += 320) {
            float s, c; sincosf(ffg[i], &s, &c);
            trig[FF_OFF + i] = make_float2(c, s);
        }
    }
    __syncthreads();

    // ---- fused phase 0+1: ring conv1 (2x2, stride 2, non-overlapping) ----
    // one thread per output position, all 4 channels
    if (tid < 196) {
        int i = tid / 14, j = tid % 14;
        const float* xb = x + (size_t)b * 784;
        float2 r0 = *(const float2*)(xb + (2 * i) * 28 + 2 * j);
        float2 r1 = *(const float2*)(xb + (2 * i + 1) * 28 + 2 * j);
        float sx[4], cx[4];
        sincosf(r0.x, &sx[0], &cx[0]);
        sincosf(r0.y, &sx[1], &cx[1]);
        sincosf(r1.x, &sx[2], &cx[2]);
        sincosf(r1.y, &sx[3], &cx[3]);
        #pragma unroll
        for (int c = 0; c < 4; c++) {
            float Y = 0.f, X = 0.f;
            #pragma unroll
            for (int e = 0; e < 4; e++) {
                float2 w = trig[W1_OFF + c * 4 + e];
                Y += sx[e] * w.x - cx[e] * w.y;   // sin(x-w)
                X += cx[e] * w.x + sx[e] * w.y;   // cos(x-w)
            }
            float inv = rsqrtf(fmaxf(X * X + Y * Y, 1e-30f));
            sc1[c * 196 + tid] = make_float2(Y * inv, X * inv);
        }
    }
    __syncthreads();

    // ---- phase 2: ring conv2 (4x4, stride 2) ----
    // item = pos*8 + oc, pos = oi*6+oj
    if (tid < 288) {
        int oc = tid & 7, p = tid >> 3;
        int oi = p / 6, oj = p % 6;
        int base = oi * 2 * 14 + oj * 2;
        float Y = 0.f, X = 0.f;
        for (int ch = 0; ch < 4; ch++) {
            #pragma unroll
            for (int ki = 0; ki < 4; ki++) {
                #pragma unroll
                for (int kj = 0; kj < 4; kj++) {
                    float2 sc = sc1[ch * 196 + base + ki * 14 + kj];
                    float2 w = trig[W2_OFF + (ch * 16 + ki * 4 + kj) * 8 + oc];
                    Y += sc.x * w.x - sc.y * w.y;
                    X += sc.y * w.x + sc.x * w.y;
                }
            }
        }
        float inv = rsqrtf(fmaxf(X * X + Y * Y, 1e-30f));
        sc2[tid] = make_float2(Y * inv, X * inv);
    }
    __syncthreads();

    // ---- phase 3: ring feed-forward, out[b][n] ----
    // 10 outputs x 32-lane k-partials; k = s*9 + i covers [0,288)
    {
        int n = tid >> 5, s = tid & 31;
        float Y = 0.f, X = 0.f;
        #pragma unroll
        for (int i = 0; i < 9; i++) {
            int k = s * 9 + i;
            float2 sc = sc2[k];
            float2 w = trig[FF_OFF + k * 10 + n];
            Y += sc.x * w.x - sc.y * w.y;
            X += sc.y * w.x + sc.x * w.y;
        }
        #pragma unroll
        for (int off = 16; off > 0; off >>= 1) {
            Y += __shfl_down(Y, off, 32);
            X += __shfl_down(X, off, 32);
        }
        if (s == 0) {
            // sin(atan2(Y, X)) = Y / sqrt(X^2 + Y^2)
            out[(size_t)b * 10 + n] = Y * rsqrtf(fmaxf(X * X + Y * Y, 1e-30f));
        }
    }
}

extern "C" void kernel_launch(void* const* d_in, const int* in_sizes, int n_in,
                              void* d_out, int out_size, void* d_ws, size_t ws_size,
                              hipStream_t stream) {
    const float* x  = (const float*)d_in[0];
    const float* w1 = (const float*)d_in[1];
    const float* w2 = (const float*)d_in[2];
    const float* ff = (const float*)d_in[3];
    float* out = (float*)d_out;
    const int B = in_sizes[0] / 784;

    if (ws_size >= NTRIG * sizeof(float2)) {
        float2* trig = (float2*)d_ws;
        precompute_trig<<<12, 256, 0, stream>>>(w1, w2, ff, trig);
        ringnn_kernel<true><<<B, 320, 0, stream>>>(x, w1, w2, ff, trig, out);
    } else {
        ringnn_kernel<false><<<B, 320, 0, stream>>>(x, w1, w2, ff, nullptr, out);
    }
}

// Round 2
// 93.068 us; speedup vs baseline: 1.1557x; 1.1557x over previous
//
#include <hip/hip_runtime.h>
#include <math.h>

// LDS trig table (float2 = {cos, sin}):
//   [0,16)   conv1_w: [oc*4 + e], e = a*2+c   (matches conv1_w flat layout)
//   [16,528) conv2_w: [e*8 + oc], e = ch*16+ki*4+kj (oc pairs contiguous -> b128)
// ff trig lives in global ws: [k*10 + n] (float2), read through L1/L2.
#define W1_OFF 0
#define W2_OFF 16
#define NTRIG_SM 528
#define NFF 2880

__global__ void precompute_ff(const float* __restrict__ ff, float2* __restrict__ out) {
    int i = blockIdx.x * blockDim.x + threadIdx.x;
    if (i < NFF) {
        float s, c; sincosf(ff[i], &s, &c);
        out[i] = make_float2(c, s);
    }
}

template <bool USE_WS>
__global__ __launch_bounds__(640) void ringnn_kernel(
    const float* __restrict__ x,
    const float* __restrict__ w1g,
    const float* __restrict__ w2g,
    const float* __restrict__ ffg,
    const float2* __restrict__ fft_ws,   // precomputed ff trig [2880] (if USE_WS)
    float* __restrict__ out)
{
    __shared__ float2 trig[NTRIG_SM];
    __shared__ float2 sc1[2 * 784];              // [img][ch*196 + i*14 + j] = {sin,cos}
    __shared__ float2 sc2[2 * 288];              // [img][p*8 + oc]          = {sin,cos}
    __shared__ float2 ff_lds[USE_WS ? 1 : NFF];  // fallback only

    const int tid = threadIdx.x;

    // ---- stage small weight trig into LDS (compute per block, hw trig) ----
    if (tid < 16) {
        float s, c; __sincosf(w1g[tid], &s, &c);
        trig[W1_OFF + tid] = make_float2(c, s);
    }
    {
        int i = tid - 64;                         // threads 64..575 cover 512
        if (i >= 0 && i < 512) {
            int oc = i >> 6, e = i & 63;
            float s, c; __sincosf(w2g[i], &s, &c);
            trig[W2_OFF + e * 8 + oc] = make_float2(c, s);
        }
    }
    if (!USE_WS) {
        for (int i = tid; i < NFF; i += 640) {
            float s, c; __sincosf(ffg[i], &s, &c);
            ff_lds[i] = make_float2(c, s);
        }
    }
    __syncthreads();

    // ---- phase 1: ring conv1 (2x2, stride 2), thread = (img, pos) ----
    if (tid < 392) {
        int img = tid / 196, pos = tid % 196;
        int i = pos / 14, j = pos % 14;
        const float* xb = x + ((size_t)blockIdx.x * 2 + img) * 784;
        float2 r0 = *(const float2*)(xb + (2 * i) * 28 + 2 * j);
        float2 r1 = *(const float2*)(xb + (2 * i + 1) * 28 + 2 * j);
        float sx[4], cx[4];
        __sincosf(r0.x, &sx[0], &cx[0]);
        __sincosf(r0.y, &sx[1], &cx[1]);
        __sincosf(r1.x, &sx[2], &cx[2]);
        __sincosf(r1.y, &sx[3], &cx[3]);
        #pragma unroll
        for (int oc = 0; oc < 4; oc++) {
            float Y = 0.f, X = 0.f;
            #pragma unroll
            for (int e = 0; e < 4; e++) {
                float2 w = trig[W1_OFF + oc * 4 + e];
                Y = fmaf(sx[e], w.x, fmaf(-cx[e], w.y, Y));   // sin(x-w)
                X = fmaf(cx[e], w.x, fmaf( sx[e], w.y, X));   // cos(x-w)
            }
            float inv = rsqrtf(fmaxf(fmaf(X, X, Y * Y), 1e-30f));
            sc1[img * 784 + oc * 196 + pos] = make_float2(Y * inv, X * inv);
        }
    }
    __syncthreads();

    // ---- phase 2: ring conv2 (4x4, stride 2) ----
    // thread = (img, p, ocpair, half); half splits taps by ki in {0,1} vs {2,3}
    if (tid < 576) {
        int img = tid / 288;
        int r = tid % 288;
        int p = r >> 3, q = r & 7;
        int ocp = q >> 1, hf = q & 1;
        int oi = p / 6, oj = p % 6;
        const float2* scb = sc1 + img * 784;
        int base = oi * 28 + oj * 2;              // float2 index into 14x14 image
        float Y0 = 0.f, X0 = 0.f, Y1 = 0.f, X1 = 0.f;
        #pragma unroll
        for (int ch = 0; ch < 4; ch++) {
            #pragma unroll
            for (int kk = 0; kk < 2; kk++) {
                int ki = hf * 2 + kk;
                #pragma unroll
                for (int jp = 0; jp < 2; jp++) {
                    int kj = jp * 2;
                    // two taps (kj, kj+1): {sin,cos} pairs, 16B aligned
                    float4 sp = *(const float4*)(scb + ch * 196 + base + ki * 14 + kj);
                    int e = ch * 16 + ki * 4 + kj;
                    // w rows e, e+1 for oc pair: (wc0,ws0,wc1,ws1)
                    float4 w0 = *(const float4*)(&trig[W2_OFF + e * 8 + ocp * 2]);
                    float4 w1 = *(const float4*)(&trig[W2_OFF + (e + 1) * 8 + ocp * 2]);
                    // tap kj: sin=sp.x cos=sp.y
                    Y0 = fmaf(sp.x, w0.x, fmaf(-sp.y, w0.y, Y0));
                    X0 = fmaf(sp.y, w0.x, fmaf( sp.x, w0.y, X0));
                    Y1 = fmaf(sp.x, w0.z, fmaf(-sp.y, w0.w, Y1));
                    X1 = fmaf(sp.y, w0.z, fmaf( sp.x, w0.w, X1));
                    // tap kj+1: sin=sp.z cos=sp.w
                    Y0 = fmaf(sp.z, w1.x, fmaf(-sp.w, w1.y, Y0));
                    X0 = fmaf(sp.w, w1.x, fmaf( sp.z, w1.y, X0));
                    Y1 = fmaf(sp.z, w1.z, fmaf(-sp.w, w1.w, Y1));
                    X1 = fmaf(sp.w, w1.z, fmaf( sp.z, w1.w, X1));
                }
            }
        }
        // combine tap-halves (partner = adjacent lane)
        Y0 += __shfl_xor(Y0, 1); X0 += __shfl_xor(X0, 1);
        Y1 += __shfl_xor(Y1, 1); X1 += __shfl_xor(X1, 1);
        float Y = hf ? Y1 : Y0;
        float X = hf ? X1 : X0;
        float inv = rsqrtf(fmaxf(fmaf(X, X, Y * Y), 1e-30f));
        sc2[img * 288 + p * 8 + ocp * 2 + hf] = make_float2(Y * inv, X * inv);
    }
    __syncthreads();

    // ---- phase 3: ring feed-forward; thread = (img, n, s) ----
    {
        int img = tid / 320;
        int r = tid % 320;
        int n = r >> 5, s = r & 31;
        const float2* scb = sc2 + img * 288;
        float Y = 0.f, X = 0.f;
        #pragma unroll
        for (int i = 0; i < 9; i++) {
            int k = s * 9 + i;
            float2 sc = scb[k];
            float2 w;
            if (USE_WS) w = fft_ws[k * 10 + n];
            else        w = ff_lds[k * 10 + n];
            Y = fmaf(sc.x, w.x, fmaf(-sc.y, w.y, Y));
            X = fmaf(sc.y, w.x, fmaf( sc.x, w.y, X));
        }
        #pragma unroll
        for (int off = 16; off > 0; off >>= 1) {
            Y += __shfl_down(Y, off, 32);
            X += __shfl_down(X, off, 32);
        }
        if (s == 0) {
            // sin(atan2(Y, X)) = Y / sqrt(X^2 + Y^2)
            size_t b = (size_t)blockIdx.x * 2 + img;
            out[b * 10 + n] = Y * rsqrtf(fmaxf(fmaf(X, X, Y * Y), 1e-30f));
        }
    }
}

extern "C" void kernel_launch(void* const* d_in, const int* in_sizes, int n_in,
                              void* d_out, int out_size, void* d_ws, size_t ws_size,
                              hipStream_t stream) {
    const float* x  = (const float*)d_in[0];
    const float* w1 = (const float*)d_in[1];
    const float* w2 = (const float*)d_in[2];
    const float* ff = (const float*)d_in[3];
    float* out = (float*)d_out;
    const int B = in_sizes[0] / 784;   // 4096

    if (ws_size >= NFF * sizeof(float2)) {
        float2* fft = (float2*)d_ws;
        precompute_ff<<<(NFF + 255) / 256, 256, 0, stream>>>(ff, fft);
        ringnn_kernel<true><<<B / 2, 640, 0, stream>>>(x, w1, w2, ff, fft, out);
    } else {
        ringnn_kernel<false><<<B / 2, 640, 0, stream>>>(x, w1, w2, ff, nullptr, out);
    }
}

// Round 3
// 91.128 us; speedup vs baseline: 1.1803x; 1.0213x over previous
//
#include <hip/hip_runtime.h>
#include <math.h>

// All-in-one kernel, no workspace (the harness's 268MB d_ws 0xAA poison was
// showing up in the timed loop at ~41us; avoid touching d_ws entirely).
//
// LDS layout (float2 = {cos,sin} for weights, {sin,cos} for activations):
//   trig1[16]  : conv1_w trig, [oc*4 + e], e = a*2+c
//   trig2[520] : conv2_w trig, [ocp*130 + e*2 + (oc&1)]  (pad 130 -> ocp groups
//                land 4 banks apart; float4 read = both oc of a pair at tap e)
//   sc1[2016]  : h1 {sin,cos}, [img*1008 + ch*252 + row*18 + col]
//                (row stride 18: keeps b128 alignment, oi-strips 8 banks apart)
//   sc2[576]   : h2 {sin,cos}, [img*288 + p*8 + oc]
#define B_PER_BLK 2

__global__ __launch_bounds__(640) void ringnn_kernel(
    const float* __restrict__ x,
    const float* __restrict__ w1g,
    const float* __restrict__ w2g,
    const float* __restrict__ ffg,
    float* __restrict__ out)
{
    __shared__ float2 trig1[16];
    __shared__ float2 trig2[520];
    __shared__ float2 sc1[B_PER_BLK * 1008];
    __shared__ float2 sc2[B_PER_BLK * 288];
    const int tid = threadIdx.x;

    // ---- stage weight trig (hw sincos; exactness not needed, thr=1.7e-2) ----
    if (tid < 16) {
        float s, c; __sincosf(w1g[tid], &s, &c);
        trig1[tid] = make_float2(c, s);
    }
    if (tid < 512) {
        int oc = tid >> 6, e = tid & 63;
        float s, c; __sincosf(w2g[tid], &s, &c);
        trig2[(oc >> 1) * 130 + e * 2 + (oc & 1)] = make_float2(c, s);
    }
    __syncthreads();

    // ---- phase 1: ring conv1 (2x2 stride 2), thread = (img, pos) ----
    if (tid < 392) {
        int img = tid / 196, pos = tid % 196;
        int i = pos / 14, j = pos % 14;
        const float* xb = x + ((size_t)blockIdx.x * B_PER_BLK + img) * 784;
        float2 r0 = *(const float2*)(xb + (2 * i) * 28 + 2 * j);
        float2 r1 = *(const float2*)(xb + (2 * i + 1) * 28 + 2 * j);
        float sx[4], cx[4];
        __sincosf(r0.x, &sx[0], &cx[0]);
        __sincosf(r0.y, &sx[1], &cx[1]);
        __sincosf(r1.x, &sx[2], &cx[2]);
        __sincosf(r1.y, &sx[3], &cx[3]);
        #pragma unroll
        for (int oc = 0; oc < 4; oc++) {
            float4 wa = *(const float4*)(&trig1[oc * 4]);      // taps e0,e1
            float4 wb = *(const float4*)(&trig1[oc * 4 + 2]);  // taps e2,e3
            float Y = 0.f, X = 0.f;
            Y = fmaf(sx[0], wa.x, fmaf(-cx[0], wa.y, Y));
            X = fmaf(cx[0], wa.x, fmaf( sx[0], wa.y, X));
            Y = fmaf(sx[1], wa.z, fmaf(-cx[1], wa.w, Y));
            X = fmaf(cx[1], wa.z, fmaf( sx[1], wa.w, X));
            Y = fmaf(sx[2], wb.x, fmaf(-cx[2], wb.y, Y));
            X = fmaf(cx[2], wb.x, fmaf( sx[2], wb.y, X));
            Y = fmaf(sx[3], wb.z, fmaf(-cx[3], wb.w, Y));
            X = fmaf(cx[3], wb.z, fmaf( sx[3], wb.w, X));
            float inv = rsqrtf(fmaxf(fmaf(X, X, Y * Y), 1e-30f));
            sc1[img * 1008 + oc * 252 + i * 18 + j] = make_float2(Y * inv, X * inv);
        }
    }
    __syncthreads();

    // ---- phase 2: ring conv2 (4x4 stride 2) ----
    // thread = (img, oi, ojg, ocp, hf): 3 oj windows share an 8-col strip,
    // 2 oc share each weight read, hf splits taps by ki{0,1}|{2,3}.
    if (tid < 192) {
        int img = tid / 96, r = tid % 96;
        int oi = r >> 4, ojg = (r >> 3) & 1, ocp = (r >> 1) & 3, hf = r & 1;
        const float2* scb = sc1 + img * 1008;
        const float2* wbp = trig2 + ocp * 130;
        float aY[3][2] = {{0.f,0.f},{0.f,0.f},{0.f,0.f}};
        float aX[3][2] = {{0.f,0.f},{0.f,0.f},{0.f,0.f}};
        #pragma unroll
        for (int ch = 0; ch < 4; ch++) {
            #pragma unroll
            for (int kk = 0; kk < 2; kk++) {
                int ki = hf * 2 + kk;
                int base = ch * 252 + (oi * 2 + ki) * 18 + ojg * 6;
                float4 f0 = *(const float4*)(scb + base);      // cols 0,1
                float4 f1 = *(const float4*)(scb + base + 2);  // cols 2,3
                float4 f2 = *(const float4*)(scb + base + 4);  // cols 4,5
                float4 f3 = *(const float4*)(scb + base + 6);  // cols 6,7
                float ss[8] = {f0.x,f0.z,f1.x,f1.z,f2.x,f2.z,f3.x,f3.z};
                float cc[8] = {f0.y,f0.w,f1.y,f1.w,f2.y,f2.w,f3.y,f3.w};
                int e0 = ch * 16 + ki * 4;
                #pragma unroll
                for (int kj = 0; kj < 4; kj++) {
                    float4 wv = *(const float4*)(wbp + (e0 + kj) * 2); // (c0,s0,c1,s1)
                    #pragma unroll
                    for (int ojl = 0; ojl < 3; ojl++) {
                        float s = ss[ojl * 2 + kj], c = cc[ojl * 2 + kj];
                        aY[ojl][0] = fmaf(s, wv.x, fmaf(-c, wv.y, aY[ojl][0]));
                        aX[ojl][0] = fmaf(c, wv.x, fmaf( s, wv.y, aX[ojl][0]));
                        aY[ojl][1] = fmaf(s, wv.z, fmaf(-c, wv.w, aY[ojl][1]));
                        aX[ojl][1] = fmaf(c, wv.z, fmaf( s, wv.w, aX[ojl][1]));
                    }
                }
            }
        }
        #pragma unroll
        for (int ojl = 0; ojl < 3; ojl++) {
            float y0 = aY[ojl][0]; y0 += __shfl_xor(y0, 1);
            float y1 = aY[ojl][1]; y1 += __shfl_xor(y1, 1);
            float x0 = aX[ojl][0]; x0 += __shfl_xor(x0, 1);
            float x1 = aX[ojl][1]; x1 += __shfl_xor(x1, 1);
            float Y = hf ? y1 : y0;
            float X = hf ? x1 : x0;
            float inv = rsqrtf(fmaxf(fmaf(X, X, Y * Y), 1e-30f));
            int p = oi * 6 + ojg * 3 + ojl;
            sc2[img * 288 + p * 8 + ocp * 2 + hf] = make_float2(Y * inv, X * inv);
        }
    }
    __syncthreads();

    // ---- phase 3: ring feed-forward; thread = (img, n, s16); ff trig inline ----
    if (tid < 320) {
        int img = tid / 160, r = tid % 160;
        int n = r >> 4, s = r & 15;
        const float2* scb = sc2 + img * 288;
        float Y = 0.f, X = 0.f;
        #pragma unroll
        for (int i = 0; i < 18; i++) {
            int k = s * 18 + i;
            float2 sc = scb[k];
            float ws_, wc_;
            __sincosf(ffg[k * 10 + n], &ws_, &wc_);
            Y = fmaf(sc.x, wc_, fmaf(-sc.y, ws_, Y));
            X = fmaf(sc.y, wc_, fmaf( sc.x, ws_, X));
        }
        #pragma unroll
        for (int off = 1; off < 16; off <<= 1) {
            Y += __shfl_xor(Y, off);
            X += __shfl_xor(X, off);
        }
        if (s == 0) {
            size_t b = (size_t)blockIdx.x * B_PER_BLK + img;
            out[b * 10 + n] = Y * rsqrtf(fmaxf(fmaf(X, X, Y * Y), 1e-30f));
        }
    }
}

extern "C" void kernel_launch(void* const* d_in, const int* in_sizes, int n_in,
                              void* d_out, int out_size, void* d_ws, size_t ws_size,
                              hipStream_t stream) {
    const float* x  = (const float*)d_in[0];
    const float* w1 = (const float*)d_in[1];
    const float* w2 = (const float*)d_in[2];
    const float* ff = (const float*)d_in[3];
    float* out = (float*)d_out;
    const int B = in_sizes[0] / 784;   // 4096
    ringnn_kernel<<<B / B_PER_BLK, 640, 0, stream>>>(x, w1, w2, ff, out);
}

// Round 4
// 89.564 us; speedup vs baseline: 1.2009x; 1.0175x over previous
//
#include <hip/hip_runtime.h>
#include <math.h>

// Insight from R3 counters: the harness re-poisons the 268MB d_ws with 0xAA
// (41us) EVERY timed iteration even if we never touch d_ws -> using d_ws is
// free. So: precompute the ff trig table TRANSPOSED [n][k] into d_ws and make
// phase 3 fully coalesced.
//
// LDS layout (float2 = {cos,sin} for weights, {sin,cos} for activations):
//   trig1[16]  : conv1_w trig, [oc*4 + e], e = a*2+c
//   trig2[520] : conv2_w trig, [ocp*130 + e*2 + (oc&1)]
//   sc1[2016]  : h1 {sin,cos}, [img*1008 + ch*252 + row*18 + col]
//   sc2[576]   : h2 {sin,cos}, [img*288 + p*8 + oc]
#define B_PER_BLK 2
#define NFF 2880

__global__ void precompute_fft(const float* __restrict__ ff,
                               float2* __restrict__ out) {
    int idx = blockIdx.x * blockDim.x + threadIdx.x;
    if (idx < NFF) {
        int k = idx / 10, n = idx % 10;
        float s, c; sincosf(ff[idx], &s, &c);
        out[n * 288 + k] = make_float2(c, s);   // transposed: [n][k]
    }
}

__global__ __launch_bounds__(640) void ringnn_kernel(
    const float* __restrict__ x,
    const float* __restrict__ w1g,
    const float* __restrict__ w2g,
    const float2* __restrict__ fft,   // [n*288 + k] = {cos,sin} of ff_w
    float* __restrict__ out)
{
    __shared__ __align__(16) float2 trig1[16];
    __shared__ __align__(16) float2 trig2[520];
    __shared__ __align__(16) float2 sc1[B_PER_BLK * 1008];
    __shared__ __align__(16) float2 sc2[B_PER_BLK * 288];
    const int tid = threadIdx.x;

    // ---- stage weight trig (hw sincos; threshold 1.7e-2, error ~1e-6) ----
    if (tid < 16) {
        float s, c; __sincosf(w1g[tid], &s, &c);
        trig1[tid] = make_float2(c, s);
    }
    if (tid < 512) {
        int oc = tid >> 6, e = tid & 63;
        float s, c; __sincosf(w2g[tid], &s, &c);
        trig2[(oc >> 1) * 130 + e * 2 + (oc & 1)] = make_float2(c, s);
    }
    __syncthreads();

    // ---- phase 1: ring conv1 (2x2 stride 2), thread = (img, pos) ----
    if (tid < 392) {
        int img = tid / 196, pos = tid % 196;
        int i = pos / 14, j = pos % 14;
        const float* xb = x + ((size_t)blockIdx.x * B_PER_BLK + img) * 784;
        float2 r0 = *(const float2*)(xb + (2 * i) * 28 + 2 * j);
        float2 r1 = *(const float2*)(xb + (2 * i + 1) * 28 + 2 * j);
        float sx[4], cx[4];
        __sincosf(r0.x, &sx[0], &cx[0]);
        __sincosf(r0.y, &sx[1], &cx[1]);
        __sincosf(r1.x, &sx[2], &cx[2]);
        __sincosf(r1.y, &sx[3], &cx[3]);
        #pragma unroll
        for (int oc = 0; oc < 4; oc++) {
            float4 wa = *(const float4*)(&trig1[oc * 4]);      // taps e0,e1
            float4 wb = *(const float4*)(&trig1[oc * 4 + 2]);  // taps e2,e3
            float Y = 0.f, X = 0.f;
            Y = fmaf(sx[0], wa.x, fmaf(-cx[0], wa.y, Y));
            X = fmaf(cx[0], wa.x, fmaf( sx[0], wa.y, X));
            Y = fmaf(sx[1], wa.z, fmaf(-cx[1], wa.w, Y));
            X = fmaf(cx[1], wa.z, fmaf( sx[1], wa.w, X));
            Y = fmaf(sx[2], wb.x, fmaf(-cx[2], wb.y, Y));
            X = fmaf(cx[2], wb.x, fmaf( sx[2], wb.y, X));
            Y = fmaf(sx[3], wb.z, fmaf(-cx[3], wb.w, Y));
            X = fmaf(cx[3], wb.z, fmaf( sx[3], wb.w, X));
            float inv = rsqrtf(fmaxf(fmaf(X, X, Y * Y), 1e-30f));
            sc1[img * 1008 + oc * 252 + i * 18 + j] = make_float2(Y * inv, X * inv);
        }
    }
    __syncthreads();

    // ---- phase 2: ring conv2 (4x4 stride 2) ----
    // thread = (img, oi, ojg, ocp, hf): 3 oj windows share an 8-col strip,
    // 2 oc share each weight read, hf splits taps by ki{0,1}|{2,3}.
    if (tid < 192) {
        int img = tid / 96, r = tid % 96;
        int oi = r >> 4, ojg = (r >> 3) & 1, ocp = (r >> 1) & 3, hf = r & 1;
        const float2* scb = sc1 + img * 1008;
        const float2* wbp = trig2 + ocp * 130;
        float aY[3][2] = {{0.f,0.f},{0.f,0.f},{0.f,0.f}};
        float aX[3][2] = {{0.f,0.f},{0.f,0.f},{0.f,0.f}};
        #pragma unroll
        for (int ch = 0; ch < 4; ch++) {
            #pragma unroll
            for (int kk = 0; kk < 2; kk++) {
                int ki = hf * 2 + kk;
                int base = ch * 252 + (oi * 2 + ki) * 18 + ojg * 6;
                float4 f0 = *(const float4*)(sc1 + img * 1008 + base);
                float4 f1 = *(const float4*)(sc1 + img * 1008 + base + 2);
                float4 f2 = *(const float4*)(sc1 + img * 1008 + base + 4);
                float4 f3 = *(const float4*)(sc1 + img * 1008 + base + 6);
                float ss[8] = {f0.x,f0.z,f1.x,f1.z,f2.x,f2.z,f3.x,f3.z};
                float cc[8] = {f0.y,f0.w,f1.y,f1.w,f2.y,f2.w,f3.y,f3.w};
                int e0 = ch * 16 + ki * 4;
                #pragma unroll
                for (int kj = 0; kj < 4; kj++) {
                    float4 wv = *(const float4*)(wbp + (e0 + kj) * 2); // (c0,s0,c1,s1)
                    #pragma unroll
                    for (int ojl = 0; ojl < 3; ojl++) {
                        float s = ss[ojl * 2 + kj], c = cc[ojl * 2 + kj];
                        aY[ojl][0] = fmaf(s, wv.x, fmaf(-c, wv.y, aY[ojl][0]));
                        aX[ojl][0] = fmaf(c, wv.x, fmaf( s, wv.y, aX[ojl][0]));
                        aY[ojl][1] = fmaf(s, wv.z, fmaf(-c, wv.w, aY[ojl][1]));
                        aX[ojl][1] = fmaf(c, wv.z, fmaf( s, wv.w, aX[ojl][1]));
                    }
                }
            }
        }
        #pragma unroll
        for (int ojl = 0; ojl < 3; ojl++) {
            float y0 = aY[ojl][0]; y0 += __shfl_xor(y0, 1);
            float y1 = aY[ojl][1]; y1 += __shfl_xor(y1, 1);
            float x0 = aX[ojl][0]; x0 += __shfl_xor(x0, 1);
            float x1 = aX[ojl][1]; x1 += __shfl_xor(x1, 1);
            float Y = hf ? y1 : y0;
            float X = hf ? x1 : x0;
            float inv = rsqrtf(fmaxf(fmaf(X, X, Y * Y), 1e-30f));
            int p = oi * 6 + ojg * 3 + ojl;
            sc2[img * 288 + p * 8 + ocp * 2 + hf] = make_float2(Y * inv, X * inv);
        }
    }
    __syncthreads();

    // ---- phase 3: ring feed-forward; thread = (img, n, s32) ----
    // All 640 threads active; k = i*32 + s -> 32 consecutive k per n-group:
    // fft reads are 256B-contiguous per group (L1-resident 23KB table),
    // sc2 LDS reads are 2-way bank aliased (free).
    {
        int img = tid / 320, r = tid % 320;
        int n = r >> 5, s = r & 31;
        const float2* scb = sc2 + img * 288;
        const float2* wn = fft + n * 288;
        float Y = 0.f, X = 0.f;
        #pragma unroll
        for (int i = 0; i < 9; i++) {
            int k = i * 32 + s;
            float2 sc = scb[k];
            float2 w = wn[k];
            Y = fmaf(sc.x, w.x, fmaf(-sc.y, w.y, Y));
            X = fmaf(sc.y, w.x, fmaf( sc.x, w.y, X));
        }
        #pragma unroll
        for (int off = 16; off > 0; off >>= 1) {
            Y += __shfl_down(Y, off, 32);
            X += __shfl_down(X, off, 32);
        }
        if (s == 0) {
            size_t b = (size_t)blockIdx.x * B_PER_BLK + img;
            out[b * 10 + n] = Y * rsqrtf(fmaxf(fmaf(X, X, Y * Y), 1e-30f));
        }
    }
}

extern "C" void kernel_launch(void* const* d_in, const int* in_sizes, int n_in,
                              void* d_out, int out_size, void* d_ws, size_t ws_size,
                              hipStream_t stream) {
    const float* x  = (const float*)d_in[0];
    const float* w1 = (const float*)d_in[1];
    const float* w2 = (const float*)d_in[2];
    const float* ff = (const float*)d_in[3];
    float* out = (float*)d_out;
    const int B = in_sizes[0] / 784;   // 4096

    float2* fft = (float2*)d_ws;       // 23KB of the (unconditionally poisoned) ws
    precompute_fft<<<(NFF + 255) / 256, 256, 0, stream>>>(ff, fft);
    ringnn_kernel<<<B / B_PER_BLK, 640, 0, stream>>>(x, w1, w2, fft, out);
}

// Round 8
// 88.287 us; speedup vs baseline: 1.2183x; 1.0145x over previous
//
#include <hip/hip_runtime.h>
#include <math.h>

// Base = R4 (last green: 89.6us, absmax 0.0). Changes vs R4, both
// index-preserving: (1) ALL weight trig precomputed into d_ws (the harness
// poisons the 268MB ws for 41us unconditionally, so using ws is free);
// in-kernel staging is now b128 copies, zero sincos. (2) x-patch loads hoisted
// to kernel top so HBM latency hides behind trig staging + barrier.
//
// d_ws trig layout (float2 = {cos,sin}):
//   [0,2880)    fft:   [n*288 + k]            (transposed ff_w trig)
//   [2880,3400) trig2: [ocp*130 + e*2 + (oc&1)], e = ch*16+ki*4+kj (pad 130)
//   [3400,3416) trig1: [oc*4 + e], e = a*2+c
#define FFT_OFF 0
#define W2_OFF 2880
#define W1_OFF 3400
#define B_PER_BLK 2

__global__ void precompute_trig(const float* __restrict__ w1,
                                const float* __restrict__ w2,
                                const float* __restrict__ ff,
                                float2* __restrict__ ws) {
    int idx = blockIdx.x * blockDim.x + threadIdx.x;
    if (idx < 2880) {
        int k = idx / 10, n = idx % 10;
        float s, c; sincosf(ff[idx], &s, &c);
        ws[FFT_OFF + n * 288 + k] = make_float2(c, s);
    } else if (idx < 3392) {
        int i = idx - 2880;                  // i = oc*64 + e
        int oc = i >> 6, e = i & 63;
        float s, c; sincosf(w2[i], &s, &c);
        ws[W2_OFF + (oc >> 1) * 130 + e * 2 + (oc & 1)] = make_float2(c, s);
    } else if (idx < 3408) {
        int i = idx - 3392;
        float s, c; sincosf(w1[i], &s, &c);
        ws[W1_OFF + i] = make_float2(c, s);
    }
}

// 640 threads, 2 images/block, 2048 blocks. LDS 25KB -> 3 blocks/CU
// (wave-limited, 30/32 waves).
__global__ __launch_bounds__(640) void ringnn_kernel(
    const float* __restrict__ x,
    const float2* __restrict__ ws,
    float* __restrict__ out)
{
    __shared__ __align__(16) float2 trig1[16];
    __shared__ __align__(16) float2 trig2[520];
    __shared__ __align__(16) float2 sc1[B_PER_BLK * 1008];  // img*1008+ch*252+row*18+col
    __shared__ __align__(16) float2 sc2[B_PER_BLK * 288];   // img*288 + p*8 + oc
    const int tid = threadIdx.x;
    const float2* __restrict__ fft = ws + FFT_OFF;

    // ---- hoisted x loads (latency hides behind trig staging + barrier) ----
    int img = tid / 196, pos = tid % 196;
    int pi = pos / 14, pj = pos % 14;
    float2 r0 = make_float2(0.f, 0.f), r1 = make_float2(0.f, 0.f);
    if (tid < 392) {
        const float* xb = x + ((size_t)blockIdx.x * B_PER_BLK + img) * 784;
        r0 = *(const float2*)(xb + (2 * pi) * 28 + 2 * pj);
        r1 = *(const float2*)(xb + (2 * pi + 1) * 28 + 2 * pj);
    }

    // ---- stage weight trig from ws: pure b128 copies, no sincos ----
    if (tid < 260) ((float4*)trig2)[tid] = ((const float4*)(ws + W2_OFF))[tid];
    else if (tid >= 512 && tid < 520)
        ((float4*)trig1)[tid - 512] = ((const float4*)(ws + W1_OFF))[tid - 512];
    __syncthreads();

    // ---- phase 1: ring conv1 (2x2 stride 2), thread = (img, pos) ----
    if (tid < 392) {
        float sx[4], cx[4];
        __sincosf(r0.x, &sx[0], &cx[0]);
        __sincosf(r0.y, &sx[1], &cx[1]);
        __sincosf(r1.x, &sx[2], &cx[2]);
        __sincosf(r1.y, &sx[3], &cx[3]);
        #pragma unroll
        for (int oc = 0; oc < 4; oc++) {
            float4 wa = *(const float4*)(&trig1[oc * 4]);      // taps e0,e1
            float4 wb = *(const float4*)(&trig1[oc * 4 + 2]);  // taps e2,e3
            float Y = 0.f, X = 0.f;
            Y = fmaf(sx[0], wa.x, fmaf(-cx[0], wa.y, Y));
            X = fmaf(cx[0], wa.x, fmaf( sx[0], wa.y, X));
            Y = fmaf(sx[1], wa.z, fmaf(-cx[1], wa.w, Y));
            X = fmaf(cx[1], wa.z, fmaf( sx[1], wa.w, X));
            Y = fmaf(sx[2], wb.x, fmaf(-cx[2], wb.y, Y));
            X = fmaf(cx[2], wb.x, fmaf( sx[2], wb.y, X));
            Y = fmaf(sx[3], wb.z, fmaf(-cx[3], wb.w, Y));
            X = fmaf(cx[3], wb.z, fmaf( sx[3], wb.w, X));
            float inv = rsqrtf(fmaxf(fmaf(X, X, Y * Y), 1e-30f));
            sc1[img * 1008 + oc * 252 + pi * 18 + pj] = make_float2(Y * inv, X * inv);
        }
    }
    __syncthreads();

    // ---- phase 2: ring conv2 (4x4 stride 2) ----
    // thread = (img, oi, ojg, ocp, hf): 3 oj windows share an 8-col strip,
    // 2 oc share each weight read, hf splits taps by ki{0,1}|{2,3}.
    if (tid < 192) {
        int im2 = tid / 96, r = tid % 96;
        int oi = r >> 4, ojg = (r >> 3) & 1, ocp = (r >> 1) & 3, hf = r & 1;
        const float2* wbp = trig2 + ocp * 130;
        float aY[3][2] = {{0.f,0.f},{0.f,0.f},{0.f,0.f}};
        float aX[3][2] = {{0.f,0.f},{0.f,0.f},{0.f,0.f}};
        #pragma unroll
        for (int ch = 0; ch < 4; ch++) {
            #pragma unroll
            for (int kk = 0; kk < 2; kk++) {
                int ki = hf * 2 + kk;
                int base = ch * 252 + (oi * 2 + ki) * 18 + ojg * 6;
                float4 f0 = *(const float4*)(sc1 + im2 * 1008 + base);
                float4 f1 = *(const float4*)(sc1 + im2 * 1008 + base + 2);
                float4 f2 = *(const float4*)(sc1 + im2 * 1008 + base + 4);
                float4 f3 = *(const float4*)(sc1 + im2 * 1008 + base + 6);
                float ss[8] = {f0.x,f0.z,f1.x,f1.z,f2.x,f2.z,f3.x,f3.z};
                float cc[8] = {f0.y,f0.w,f1.y,f1.w,f2.y,f2.w,f3.y,f3.w};
                int e0 = ch * 16 + ki * 4;
                #pragma unroll
                for (int kj = 0; kj < 4; kj++) {
                    float4 wv = *(const float4*)(wbp + (e0 + kj) * 2); // (c0,s0,c1,s1)
                    #pragma unroll
                    for (int ojl = 0; ojl < 3; ojl++) {
                        float s = ss[ojl * 2 + kj], c = cc[ojl * 2 + kj];
                        aY[ojl][0] = fmaf(s, wv.x, fmaf(-c, wv.y, aY[ojl][0]));
                        aX[ojl][0] = fmaf(c, wv.x, fmaf( s, wv.y, aX[ojl][0]));
                        aY[ojl][1] = fmaf(s, wv.z, fmaf(-c, wv.w, aY[ojl][1]));
                        aX[ojl][1] = fmaf(c, wv.z, fmaf( s, wv.w, aX[ojl][1]));
                    }
                }
            }
        }
        #pragma unroll
        for (int ojl = 0; ojl < 3; ojl++) {
            float y0 = aY[ojl][0]; y0 += __shfl_xor(y0, 1);
            float y1 = aY[ojl][1]; y1 += __shfl_xor(y1, 1);
            float x0 = aX[ojl][0]; x0 += __shfl_xor(x0, 1);
            float x1 = aX[ojl][1]; x1 += __shfl_xor(x1, 1);
            float Y = hf ? y1 : y0;
            float X = hf ? x1 : x0;
            float inv = rsqrtf(fmaxf(fmaf(X, X, Y * Y), 1e-30f));
            int p = oi * 6 + ojg * 3 + ojl;
            sc2[im2 * 288 + p * 8 + ocp * 2 + hf] = make_float2(Y * inv, X * inv);
        }
    }
    __syncthreads();

    // ---- phase 3: ring feed-forward; thread = (img, n, s32) ----
    {
        int im3 = tid / 320, r = tid % 320;
        int n = r >> 5, s = r & 31;
        const float2* scb = sc2 + im3 * 288;
        const float2* wn = fft + n * 288;
        float Y = 0.f, X = 0.f;
        #pragma unroll
        for (int i = 0; i < 9; i++) {
            int k = i * 32 + s;
            float2 sc = scb[k];
            float2 w = wn[k];
            Y = fmaf(sc.x, w.x, fmaf(-sc.y, w.y, Y));
            X = fmaf(sc.y, w.x, fmaf( sc.x, w.y, X));
        }
        #pragma unroll
        for (int off = 16; off > 0; off >>= 1) {
            Y += __shfl_down(Y, off, 32);
            X += __shfl_down(X, off, 32);
        }
        if (s == 0) {
            size_t b = (size_t)blockIdx.x * B_PER_BLK + im3;
            out[b * 10 + n] = Y * rsqrtf(fmaxf(fmaf(X, X, Y * Y), 1e-30f));
        }
    }
}

extern "C" void kernel_launch(void* const* d_in, const int* in_sizes, int n_in,
                              void* d_out, int out_size, void* d_ws, size_t ws_size,
                              hipStream_t stream) {
    const float* x  = (const float*)d_in[0];
    const float* w1 = (const float*)d_in[1];
    const float* w2 = (const float*)d_in[2];
    const float* ff = (const float*)d_in[3];
    float* out = (float*)d_out;
    const int B = in_sizes[0] / 784;   // 4096

    float2* ws = (float2*)d_ws;
    precompute_trig<<<14, 256, 0, stream>>>(w1, w2, ff, ws);
    ringnn_kernel<<<B / B_PER_BLK, 640, 0, stream>>>(x, ws, out);
}

// Round 9
// 86.962 us; speedup vs baseline: 1.2368x; 1.0152x over previous
//
#include <hip/hip_runtime.h>
#include <math.h>

// Base = R8 (green: 88.3us, absmax 0.0). R9 change: B_PER_BLK 2 -> 1 with
// 320-thread blocks (5 waves), grid 4096. Per-image arithmetic is BITWISE
// IDENTICAL to R8 (same P1/P2/P3 bodies, same FMA and shuffle order) -- R5/R7
// showed summation order upstream of the normalizations is load-bearing.
// Rationale: R8 ran P2 (57% of issue cycles) on 3/10 waves with only 3
// blocks/CU resident; 5-wave blocks give ~6 blocks/CU and finer cross-block
// phase stagger to fill the barrier shadows.
//
// d_ws trig layout (float2 = {cos,sin}):
//   [0,2880)    fft:   [n*288 + k]            (transposed ff_w trig)
//   [2880,3400) trig2: [ocp*130 + e*2 + (oc&1)], e = ch*16+ki*4+kj (pad 130)
//   [3400,3416) trig1: [oc*4 + e], e = a*2+c
#define FFT_OFF 0
#define W2_OFF 2880
#define W1_OFF 3400

__global__ void precompute_trig(const float* __restrict__ w1,
                                const float* __restrict__ w2,
                                const float* __restrict__ ff,
                                float2* __restrict__ ws) {
    int idx = blockIdx.x * blockDim.x + threadIdx.x;
    if (idx < 2880) {
        int k = idx / 10, n = idx % 10;
        float s, c; sincosf(ff[idx], &s, &c);
        ws[FFT_OFF + n * 288 + k] = make_float2(c, s);
    } else if (idx < 3392) {
        int i = idx - 2880;                  // i = oc*64 + e
        int oc = i >> 6, e = i & 63;
        float s, c; sincosf(w2[i], &s, &c);
        ws[W2_OFF + (oc >> 1) * 130 + e * 2 + (oc & 1)] = make_float2(c, s);
    } else if (idx < 3408) {
        int i = idx - 3392;
        float s, c; sincosf(w1[i], &s, &c);
        ws[W1_OFF + i] = make_float2(c, s);
    }
}

// 320 threads = 5 waves, 1 image/block, 4096 blocks.
// LDS: trig1 16f2 + trig2 520f2 + sc1 1008f2 + sc2 288f2 = 14.7KB.
__global__ __launch_bounds__(320) void ringnn_kernel(
    const float* __restrict__ x,
    const float2* __restrict__ ws,
    float* __restrict__ out)
{
    __shared__ __align__(16) float2 trig1[16];
    __shared__ __align__(16) float2 trig2[520];
    __shared__ __align__(16) float2 sc1[1008];  // ch*252 + row*18 + col
    __shared__ __align__(16) float2 sc2[288];   // p*8 + oc
    const int tid = threadIdx.x;
    const float2* __restrict__ fft = ws + FFT_OFF;

    // ---- hoisted x loads (latency hides behind trig staging + barrier) ----
    int pi = (tid % 196) / 14, pj = tid % 14;
    float2 r0 = make_float2(0.f, 0.f), r1 = make_float2(0.f, 0.f);
    if (tid < 196) {
        const float* xb = x + (size_t)blockIdx.x * 784;
        r0 = *(const float2*)(xb + (2 * pi) * 28 + 2 * pj);
        r1 = *(const float2*)(xb + (2 * pi + 1) * 28 + 2 * pj);
    }

    // ---- stage weight trig from ws: pure b128 copies, no sincos ----
    if (tid < 260) ((float4*)trig2)[tid] = ((const float4*)(ws + W2_OFF))[tid];
    else if (tid < 268)
        ((float4*)trig1)[tid - 260] = ((const float4*)(ws + W1_OFF))[tid - 260];
    __syncthreads();

    // ---- phase 1: ring conv1 (2x2 stride 2), thread = pos ----
    if (tid < 196) {
        float sx[4], cx[4];
        __sincosf(r0.x, &sx[0], &cx[0]);
        __sincosf(r0.y, &sx[1], &cx[1]);
        __sincosf(r1.x, &sx[2], &cx[2]);
        __sincosf(r1.y, &sx[3], &cx[3]);
        #pragma unroll
        for (int oc = 0; oc < 4; oc++) {
            float4 wa = *(const float4*)(&trig1[oc * 4]);      // taps e0,e1
            float4 wb = *(const float4*)(&trig1[oc * 4 + 2]);  // taps e2,e3
            float Y = 0.f, X = 0.f;
            Y = fmaf(sx[0], wa.x, fmaf(-cx[0], wa.y, Y));
            X = fmaf(cx[0], wa.x, fmaf( sx[0], wa.y, X));
            Y = fmaf(sx[1], wa.z, fmaf(-cx[1], wa.w, Y));
            X = fmaf(cx[1], wa.z, fmaf( sx[1], wa.w, X));
            Y = fmaf(sx[2], wb.x, fmaf(-cx[2], wb.y, Y));
            X = fmaf(cx[2], wb.x, fmaf( sx[2], wb.y, X));
            Y = fmaf(sx[3], wb.z, fmaf(-cx[3], wb.w, Y));
            X = fmaf(cx[3], wb.z, fmaf( sx[3], wb.w, X));
            float inv = rsqrtf(fmaxf(fmaf(X, X, Y * Y), 1e-30f));
            sc1[oc * 252 + pi * 18 + pj] = make_float2(Y * inv, X * inv);
        }
    }
    __syncthreads();

    // ---- phase 2: ring conv2 (4x4 stride 2) ----
    // thread = (oi, ojg, ocp, hf): 3 oj windows share an 8-col strip,
    // 2 oc share each weight read, hf splits taps by ki{0,1}|{2,3}.
    if (tid < 96) {
        int r = tid;
        int oi = r >> 4, ojg = (r >> 3) & 1, ocp = (r >> 1) & 3, hf = r & 1;
        const float2* wbp = trig2 + ocp * 130;
        float aY[3][2] = {{0.f,0.f},{0.f,0.f},{0.f,0.f}};
        float aX[3][2] = {{0.f,0.f},{0.f,0.f},{0.f,0.f}};
        #pragma unroll
        for (int ch = 0; ch < 4; ch++) {
            #pragma unroll
            for (int kk = 0; kk < 2; kk++) {
                int ki = hf * 2 + kk;
                int base = ch * 252 + (oi * 2 + ki) * 18 + ojg * 6;
                float4 f0 = *(const float4*)(sc1 + base);
                float4 f1 = *(const float4*)(sc1 + base + 2);
                float4 f2 = *(const float4*)(sc1 + base + 4);
                float4 f3 = *(const float4*)(sc1 + base + 6);
                float ss[8] = {f0.x,f0.z,f1.x,f1.z,f2.x,f2.z,f3.x,f3.z};
                float cc[8] = {f0.y,f0.w,f1.y,f1.w,f2.y,f2.w,f3.y,f3.w};
                int e0 = ch * 16 + ki * 4;
                #pragma unroll
                for (int kj = 0; kj < 4; kj++) {
                    float4 wv = *(const float4*)(wbp + (e0 + kj) * 2); // (c0,s0,c1,s1)
                    #pragma unroll
                    for (int ojl = 0; ojl < 3; ojl++) {
                        float s = ss[ojl * 2 + kj], c = cc[ojl * 2 + kj];
                        aY[ojl][0] = fmaf(s, wv.x, fmaf(-c, wv.y, aY[ojl][0]));
                        aX[ojl][0] = fmaf(c, wv.x, fmaf( s, wv.y, aX[ojl][0]));
                        aY[ojl][1] = fmaf(s, wv.z, fmaf(-c, wv.w, aY[ojl][1]));
                        aX[ojl][1] = fmaf(c, wv.z, fmaf( s, wv.w, aX[ojl][1]));
                    }
                }
            }
        }
        #pragma unroll
        for (int ojl = 0; ojl < 3; ojl++) {
            float y0 = aY[ojl][0]; y0 += __shfl_xor(y0, 1);
            float y1 = aY[ojl][1]; y1 += __shfl_xor(y1, 1);
            float x0 = aX[ojl][0]; x0 += __shfl_xor(x0, 1);
            float x1 = aX[ojl][1]; x1 += __shfl_xor(x1, 1);
            float Y = hf ? y1 : y0;
            float X = hf ? x1 : x0;
            float inv = rsqrtf(fmaxf(fmaf(X, X, Y * Y), 1e-30f));
            int p = oi * 6 + ojg * 3 + ojl;
            sc2[p * 8 + ocp * 2 + hf] = make_float2(Y * inv, X * inv);
        }
    }
    __syncthreads();

    // ---- phase 3: ring feed-forward; thread = (n, s32) ----
    {
        int n = tid >> 5, s = tid & 31;
        const float2* wn = fft + n * 288;
        float Y = 0.f, X = 0.f;
        #pragma unroll
        for (int i = 0; i < 9; i++) {
            int k = i * 32 + s;
            float2 sc = sc2[k];
            float2 w = wn[k];
            Y = fmaf(sc.x, w.x, fmaf(-sc.y, w.y, Y));
            X = fmaf(sc.y, w.x, fmaf( sc.x, w.y, X));
        }
        #pragma unroll
        for (int off = 16; off > 0; off >>= 1) {
            Y += __shfl_down(Y, off, 32);
            X += __shfl_down(X, off, 32);
        }
        if (s == 0) {
            out[(size_t)blockIdx.x * 10 + n] =
                Y * rsqrtf(fmaxf(fmaf(X, X, Y * Y), 1e-30f));
        }
    }
}

extern "C" void kernel_launch(void* const* d_in, const int* in_sizes, int n_in,
                              void* d_out, int out_size, void* d_ws, size_t ws_size,
                              hipStream_t stream) {
    const float* x  = (const float*)d_in[0];
    const float* w1 = (const float*)d_in[1];
    const float* w2 = (const float*)d_in[2];
    const float* ff = (const float*)d_in[3];
    float* out = (float*)d_out;
    const int B = in_sizes[0] / 784;   // 4096

    float2* ws = (float2*)d_ws;
    precompute_trig<<<14, 256, 0, stream>>>(w1, w2, ff, ws);
    ringnn_kernel<<<B, 320, 0, stream>>>(x, ws, out);
}

// Round 11
// 85.775 us; speedup vs baseline: 1.2540x; 1.0138x over previous
//
#include <hip/hip_runtime.h>
#include <math.h>

// Base = R9 (green: 87.0us, absmax 0.0). R10/R11 changes, both zero-reorder:
//  (1) trig1 (conv1 weight trig, 16 float2) is read DIRECTLY from ws global
//      with wave-uniform addresses -> s_load / L1 broadcast, eliminating the
//      32 ds_read_b128 per block that R9 spent reading it from LDS.
//  (2) P1 therefore reads no LDS at all -> the first __syncthreads is gone;
//      a single barrier covers trig2 staging + sc1 writes before P2.
// P1/P2/P3 arithmetic (FMA + shuffle order) is BITWISE IDENTICAL to R9.
// (R10 submission hit an infra failure: "container failed twice" -- resubmit.)
//
// d_ws trig layout (float2 = {cos,sin}):
//   [0,2880)    fft:   [n*288 + k]            (transposed ff_w trig)
//   [2880,3400) trig2: [ocp*130 + e*2 + (oc&1)], e = ch*16+ki*4+kj (pad 130)
//   [3400,3416) trig1: [oc*4 + e], e = a*2+c
#define FFT_OFF 0
#define W2_OFF 2880
#define W1_OFF 3400

__global__ void precompute_trig(const float* __restrict__ w1,
                                const float* __restrict__ w2,
                                const float* __restrict__ ff,
                                float2* __restrict__ ws) {
    int idx = blockIdx.x * blockDim.x + threadIdx.x;
    if (idx < 2880) {
        int k = idx / 10, n = idx % 10;
        float s, c; sincosf(ff[idx], &s, &c);
        ws[FFT_OFF + n * 288 + k] = make_float2(c, s);
    } else if (idx < 3392) {
        int i = idx - 2880;                  // i = oc*64 + e
        int oc = i >> 6, e = i & 63;
        float s, c; sincosf(w2[i], &s, &c);
        ws[W2_OFF + (oc >> 1) * 130 + e * 2 + (oc & 1)] = make_float2(c, s);
    } else if (idx < 3408) {
        int i = idx - 3392;
        float s, c; sincosf(w1[i], &s, &c);
        ws[W1_OFF + i] = make_float2(c, s);
    }
}

// 320 threads = 5 waves, 1 image/block, 4096 blocks.
// LDS: trig2 520f2 + sc1 1008f2 + sc2 288f2 = 14.5KB.
__global__ __launch_bounds__(320) void ringnn_kernel(
    const float* __restrict__ x,
    const float2* __restrict__ ws,
    float* __restrict__ out)
{
    __shared__ __align__(16) float2 trig2[520];
    __shared__ __align__(16) float2 sc1[1008];  // ch*252 + row*18 + col
    __shared__ __align__(16) float2 sc2[288];   // p*8 + oc
    const int tid = threadIdx.x;
    const float2* __restrict__ fft = ws + FFT_OFF;
    const float2* __restrict__ w1t = ws + W1_OFF;

    // ---- hoisted x loads (latency hides behind trig2 staging) ----
    int pi = (tid % 196) / 14, pj = tid % 14;
    float2 r0 = make_float2(0.f, 0.f), r1 = make_float2(0.f, 0.f);
    if (tid < 196) {
        const float* xb = x + (size_t)blockIdx.x * 784;
        r0 = *(const float2*)(xb + (2 * pi) * 28 + 2 * pj);
        r1 = *(const float2*)(xb + (2 * pi + 1) * 28 + 2 * pj);
    }

    // ---- stage trig2 from ws: pure b128 copies, no sincos ----
    if (tid < 260) ((float4*)trig2)[tid] = ((const float4*)(ws + W2_OFF))[tid];

    // ---- phase 1: ring conv1 (2x2 stride 2), thread = pos ----
    // trig1 read from global with wave-uniform address -> scalar load path;
    // P1 touches no LDS except the sc1 writes.
    if (tid < 196) {
        float sx[4], cx[4];
        __sincosf(r0.x, &sx[0], &cx[0]);
        __sincosf(r0.y, &sx[1], &cx[1]);
        __sincosf(r1.x, &sx[2], &cx[2]);
        __sincosf(r1.y, &sx[3], &cx[3]);
        #pragma unroll
        for (int oc = 0; oc < 4; oc++) {
            float4 wa = *(const float4*)(w1t + oc * 4);      // taps e0,e1 (uniform)
            float4 wb = *(const float4*)(w1t + oc * 4 + 2);  // taps e2,e3 (uniform)
            float Y = 0.f, X = 0.f;
            Y = fmaf(sx[0], wa.x, fmaf(-cx[0], wa.y, Y));
            X = fmaf(cx[0], wa.x, fmaf( sx[0], wa.y, X));
            Y = fmaf(sx[1], wa.z, fmaf(-cx[1], wa.w, Y));
            X = fmaf(cx[1], wa.z, fmaf( sx[1], wa.w, X));
            Y = fmaf(sx[2], wb.x, fmaf(-cx[2], wb.y, Y));
            X = fmaf(cx[2], wb.x, fmaf( sx[2], wb.y, X));
            Y = fmaf(sx[3], wb.z, fmaf(-cx[3], wb.w, Y));
            X = fmaf(cx[3], wb.z, fmaf( sx[3], wb.w, X));
            float inv = rsqrtf(fmaxf(fmaf(X, X, Y * Y), 1e-30f));
            sc1[oc * 252 + pi * 18 + pj] = make_float2(Y * inv, X * inv);
        }
    }
    __syncthreads();   // single barrier: covers trig2 staging AND sc1 writes

    // ---- phase 2: ring conv2 (4x4 stride 2) ----
    // thread = (oi, ojg, ocp, hf): 3 oj windows share an 8-col strip,
    // 2 oc share each weight read, hf splits taps by ki{0,1}|{2,3}.
    if (tid < 96) {
        int r = tid;
        int oi = r >> 4, ojg = (r >> 3) & 1, ocp = (r >> 1) & 3, hf = r & 1;
        const float2* wbp = trig2 + ocp * 130;
        float aY[3][2] = {{0.f,0.f},{0.f,0.f},{0.f,0.f}};
        float aX[3][2] = {{0.f,0.f},{0.f,0.f},{0.f,0.f}};
        #pragma unroll
        for (int ch = 0; ch < 4; ch++) {
            #pragma unroll
            for (int kk = 0; kk < 2; kk++) {
                int ki = hf * 2 + kk;
                int base = ch * 252 + (oi * 2 + ki) * 18 + ojg * 6;
                float4 f0 = *(const float4*)(sc1 + base);
                float4 f1 = *(const float4*)(sc1 + base + 2);
                float4 f2 = *(const float4*)(sc1 + base + 4);
                float4 f3 = *(const float4*)(sc1 + base + 6);
                float ss[8] = {f0.x,f0.z,f1.x,f1.z,f2.x,f2.z,f3.x,f3.z};
                float cc[8] = {f0.y,f0.w,f1.y,f1.w,f2.y,f2.w,f3.y,f3.w};
                int e0 = ch * 16 + ki * 4;
                #pragma unroll
                for (int kj = 0; kj < 4; kj++) {
                    float4 wv = *(const float4*)(wbp + (e0 + kj) * 2); // (c0,s0,c1,s1)
                    #pragma unroll
                    for (int ojl = 0; ojl < 3; ojl++) {
                        float s = ss[ojl * 2 + kj], c = cc[ojl * 2 + kj];
                        aY[ojl][0] = fmaf(s, wv.x, fmaf(-c, wv.y, aY[ojl][0]));
                        aX[ojl][0] = fmaf(c, wv.x, fmaf( s, wv.y, aX[ojl][0]));
                        aY[ojl][1] = fmaf(s, wv.z, fmaf(-c, wv.w, aY[ojl][1]));
                        aX[ojl][1] = fmaf(c, wv.z, fmaf( s, wv.w, aX[ojl][1]));
                    }
                }
            }
        }
        #pragma unroll
        for (int ojl = 0; ojl < 3; ojl++) {
            float y0 = aY[ojl][0]; y0 += __shfl_xor(y0, 1);
            float y1 = aY[ojl][1]; y1 += __shfl_xor(y1, 1);
            float x0 = aX[ojl][0]; x0 += __shfl_xor(x0, 1);
            float x1 = aX[ojl][1]; x1 += __shfl_xor(x1, 1);
            float Y = hf ? y1 : y0;
            float X = hf ? x1 : x0;
            float inv = rsqrtf(fmaxf(fmaf(X, X, Y * Y), 1e-30f));
            int p = oi * 6 + ojg * 3 + ojl;
            sc2[p * 8 + ocp * 2 + hf] = make_float2(Y * inv, X * inv);
        }
    }
    __syncthreads();

    // ---- phase 3: ring feed-forward; thread = (n, s32) ----
    {
        int n = tid >> 5, s = tid & 31;
        const float2* wn = fft + n * 288;
        float Y = 0.f, X = 0.f;
        #pragma unroll
        for (int i = 0; i < 9; i++) {
            int k = i * 32 + s;
            float2 sc = sc2[k];
            float2 w = wn[k];
            Y = fmaf(sc.x, w.x, fmaf(-sc.y, w.y, Y));
            X = fmaf(sc.y, w.x, fmaf( sc.x, w.y, X));
        }
        #pragma unroll
        for (int off = 16; off > 0; off >>= 1) {
            Y += __shfl_down(Y, off, 32);
            X += __shfl_down(X, off, 32);
        }
        if (s == 0) {
            out[(size_t)blockIdx.x * 10 + n] =
                Y * rsqrtf(fmaxf(fmaf(X, X, Y * Y), 1e-30f));
        }
    }
}

extern "C" void kernel_launch(void* const* d_in, const int* in_sizes, int n_in,
                              void* d_out, int out_size, void* d_ws, size_t ws_size,
                              hipStream_t stream) {
    const float* x  = (const float*)d_in[0];
    const float* w1 = (const float*)d_in[1];
    const float* w2 = (const float*)d_in[2];
    const float* ff = (const float*)d_in[3];
    float* out = (float*)d_out;
    const int B = in_sizes[0] / 784;   // 4096

    float2* ws = (float2*)d_ws;
    precompute_trig<<<14, 256, 0, stream>>>(w1, w2, ff, ws);
    ringnn_kernel<<<B, 320, 0, stream>>>(x, ws, out);
}